// Round 10
// baseline (7570.535 us; speedup 1.0000x reference)
//
#include <hip/hip_runtime.h>
#include <math.h>

typedef short bf16x8 __attribute__((ext_vector_type(8)));
typedef float f32x4 __attribute__((ext_vector_type(4)));
typedef unsigned int uint32;

#define BETA 10.0f
#define THRESH -80.0f
// 32-dim certificate: true arg = -B*d2_64 <= -B*d2_32 =
//   20*(x.c)_32 - B*||x||^2_32 - B*||c||^2_32  (computed in bf16 MFMA).
// bf16 rtne errors add <= ~8 after *20. Not fired => true arg <= -72 =>
// contribution <= exp(-72)*1024*0.02 ~ 1e-29 << 1.5e-2 threshold.
// P(2*chi2_32 < 8) ~ 4e-10/pair -> ~0.03 expected firings over 67M pairs;
// if fired, cold path recomputes exact fp32 over all 64 dims.

// LDS map (74.25 KB -> 2 blocks/CU with VGPR <= 128)
#define C_OFF   0        // 65536 B: centers lo-32-dim bf16, chunk layout
#define XB_OFF  65536    // 8192 B: x lo-32-dim bf16, chunk layout (128 rows)
#define W_OFF   73728    // 768 B: W_x fp32 [3][64]
#define RED_OFF 74496    // 1536 B: out accumulator [128][3]
#define LDS_TOT 76032

__device__ __forceinline__ uint32 f2bf_rtne(float f) {
    uint32 u = __float_as_uint(f);
    u += 0x7FFFu + ((u >> 16) & 1u);
    return u >> 16;
}
__device__ __forceinline__ uint32 pk_rtne(float a, float b) {
    return f2bf_rtne(a) | (f2bf_rtne(b) << 16);
}
__device__ __forceinline__ f32x4 vmax4(f32x4 a, f32x4 b) {
    f32x4 r;
    r[0] = fmaxf(a[0], b[0]); r[1] = fmaxf(a[1], b[1]);
    r[2] = fmaxf(a[2], b[2]); r[3] = fmaxf(a[3], b[3]);
    return r;
}
#define MFMA __builtin_amdgcn_mfma_f32_16x16x32_bf16

// Single kernel. Block = 128 rows x 1024 centers (certificate over dims
// 0..31 only). 512 thr = 8 waves; wave = all 128 rows x 128-col group.
// Grid 512 = 2 blocks/CU: independent blocks interleave phases (no shared
// barriers), hiding staging/barrier latency. All global streams row-linear.
__global__ __launch_bounds__(512, 4) void rbfn_fused(
    const float* __restrict__ x,
    const float* __restrict__ centers,
    const float* __restrict__ W,
    const float* __restrict__ bias,
    float* __restrict__ out)
{
    __shared__ __align__(16) char lds[LDS_TOT];

    const int tid = threadIdx.x;
    const int wv = tid >> 6;
    const int lane = tid & 63;
    const int quad = lane >> 4;
    const int l15 = lane & 15;
    const int row0 = blockIdx.x * 128;
    const f32x4 z = {0.f, 0.f, 0.f, 0.f};

    const float bb0 = bias[0], bb1 = bias[1], bb2 = bias[2];

    // ---- stage centers lo-half -> bf16 chunk layout ----
    // f in [0,8192) = 1024 rows x 8 lo-segs; reads are 128-B-contiguous per
    // 8 lanes (full 64-B lines); chunk c of col j at (j>>4)*1024+c*256+(j&15)*16
    #pragma unroll
    for (int i = 0; i < 16; ++i) {
        const int f = i * 512 + tid;
        const int j = f >> 3, sg = f & 7;
        const float4 v = *((const float4*)centers + j * 16 + sg);
        uint2 q; q.x = pk_rtne(v.x, v.y); q.y = pk_rtne(v.z, v.w);
        *(uint2*)(lds + C_OFF + (j >> 4) * 1024 + (sg >> 1) * 256 +
                  (j & 15) * 16 + (sg & 1) * 8) = q;
    }
    // ---- stage x lo-half (128 rows) -> bf16 chunk layout ----
    #pragma unroll
    for (int i = 0; i < 2; ++i) {
        const int f = i * 512 + tid;
        const int r = f >> 3, sg = f & 7;
        const float4 v = *((const float4*)(x + (size_t)row0 * 64) + r * 16 + sg);
        uint2 q; q.x = pk_rtne(v.x, v.y); q.y = pk_rtne(v.z, v.w);
        *(uint2*)(lds + XB_OFF + (r >> 4) * 1024 + (sg >> 1) * 256 +
                  (r & 15) * 16 + (sg & 1) * 8) = q;
    }
    // ---- W_x (3x64 fp32) -> LDS ----
    if (tid < 48) {
        const int k = tid >> 4, c = tid & 15;
        *((float4*)(lds + W_OFF) + tid) = *((const float4*)(W + k * 1088) + c);
    }
    __syncthreads();   // barrier 1: staging complete

    // ---- exact fp32 x@Wx^T + bias -> red. thread = (row r, quarter e) ----
    {
        const int r = tid >> 2, e = tid & 3;
        const float4* xr = (const float4*)(x + (size_t)(row0 + r) * 64) + e * 4;
        const float4 a0 = xr[0], a1 = xr[1], a2 = xr[2], a3 = xr[3];
        const float4 av[4] = {a0, a1, a2, a3};
        float d0 = 0.f, d1 = 0.f, d2 = 0.f;
        #pragma unroll
        for (int i = 0; i < 4; ++i) {
            const float4 a = av[i];
            const float4 w0 = *((const float4*)(lds + W_OFF) + 0 * 16 + e * 4 + i);
            const float4 w1 = *((const float4*)(lds + W_OFF) + 1 * 16 + e * 4 + i);
            const float4 w2 = *((const float4*)(lds + W_OFF) + 2 * 16 + e * 4 + i);
            d0 = fmaf(a.w, w0.w, fmaf(a.z, w0.z, fmaf(a.y, w0.y, fmaf(a.x, w0.x, d0))));
            d1 = fmaf(a.w, w1.w, fmaf(a.z, w1.z, fmaf(a.y, w1.y, fmaf(a.x, w1.x, d1))));
            d2 = fmaf(a.w, w2.w, fmaf(a.z, w2.z, fmaf(a.y, w2.y, fmaf(a.x, w2.x, d2))));
        }
        #pragma unroll
        for (int m = 1; m <= 2; m <<= 1) {
            d0 += __shfl_xor(d0, m);
            d1 += __shfl_xor(d1, m);
            d2 += __shfl_xor(d2, m);
        }
        if (e == 0) {
            float* red = (float*)(lds + RED_OFF);
            red[r * 3 + 0] = d0 + bb0;
            red[r * 3 + 1] = d1 + bb1;
            red[r * 3 + 2] = d2 + bb2;
        }
    }

    // ---- A fragments (lo 32 dims): contiguous b128 stripes ----
    bf16x8 af[8];
    #pragma unroll
    for (int rt = 0; rt < 8; ++rt)
        af[rt] = *(const bf16x8*)(lds + XB_OFF + rt * 1024 + quad * 256 + l15 * 16);

    // ---- prermax via Gram diagonal of af ----
    float mn = 1e30f;
    #pragma unroll
    for (int rt = 0; rt < 8; ++rt) {
        const f32x4 d = MFMA(af[rt], af[rt], z, 0, 0, 0);
        #pragma unroll
        for (int reg = 0; reg < 4; ++reg)
            mn = fminf(mn, __shfl(d[reg], quad * 20 + reg));
    }
    const float prermax = -BETA * mn;

    // ---- B fragments + -BETA*||c||^2_32 via Gram diagonal ----
    bf16x8 bf[8];
    float c2r[8];
    #pragma unroll
    for (int ct = 0; ct < 8; ++ct) {
        bf[ct] = *(const bf16x8*)(lds + C_OFF + (wv * 8 + ct) * 1024 +
                                  quad * 256 + l15 * 16);
        const f32x4 d = MFMA(bf[ct], bf[ct], z, 0, 0, 0);
        const float dv = (l15 & 2) ? ((l15 & 1) ? d[3] : d[2])
                                   : ((l15 & 1) ? d[1] : d[0]);
        c2r[ct] = -BETA * __shfl(dv, (l15 >> 2) * 16 + l15);
    }
    __syncthreads();   // barrier 2: red seeded before any cold atomics

    // ---- hot loop: 8 col-tiles x 8 row-tiles, zero memory ops ----
    float gm = -1e30f;
    #pragma unroll
    for (int ct = 0; ct < 8; ++ct) {
        f32x4 m0 = {-1e30f, -1e30f, -1e30f, -1e30f};
        #pragma unroll
        for (int rt = 0; rt < 8; ++rt) {
            const f32x4 acc = MFMA(af[rt], bf[ct], z, 0, 0, 0);
            m0 = vmax4(m0, acc);
        }
        const float m = fmaxf(fmaxf(m0[0], m0[1]), fmaxf(m0[2], m0[3]));
        gm = fmaxf(gm, fmaf(2.0f * BETA, m, c2r[ct]));
    }
    const float bound = gm + prermax;

    // ---- cold exact path (statistically never; unconditional safety) ----
    if (__builtin_expect(__ballot(bound > THRESH) != 0ull, 0)) {
        float* red = (float*)(lds + RED_OFF);
        #pragma clang loop unroll(disable)
        for (int ct = 0; ct < 8; ++ct) {
            const int j = wv * 128 + ct * 16 + l15;
            #pragma clang loop unroll(disable)
            for (int rr = 0; rr < 32; ++rr) {
                const int r = (rr >> 2) * 16 + quad * 4 + (rr & 3);
                const float* xr = x + (size_t)(row0 + r) * 64;
                const float* cr = centers + (size_t)j * 64;
                float d2 = 0.f;
                #pragma clang loop unroll(disable)
                for (int k = 0; k < 64; ++k) {
                    const float df = xr[k] - cr[k];
                    d2 = fmaf(df, df, d2);
                }
                const float arg = -BETA * d2;
                if (arg > -87.f) {
                    const float e = expf(arg);
                    atomicAdd(&red[r * 3 + 0], e * W[0 * 1088 + 64 + j]);
                    atomicAdd(&red[r * 3 + 1], e * W[1 * 1088 + 64 + j]);
                    atomicAdd(&red[r * 3 + 2], e * W[2 * 1088 + 64 + j]);
                }
            }
        }
    }
    __syncthreads();   // barrier 3: red final

    // ---- coalesced float4 store ----
    if (tid < 96)
        ((float4*)out)[blockIdx.x * 96 + tid] = *((const float4*)(lds + RED_OFF) + tid);
}

extern "C" void kernel_launch(void* const* d_in, const int* in_sizes, int n_in,
                              void* d_out, int out_size, void* d_ws, size_t ws_size,
                              hipStream_t stream) {
    const float* x       = (const float*)d_in[0];
    const float* centers = (const float*)d_in[1];
    const float* W       = (const float*)d_in[2];
    const float* b       = (const float*)d_in[3];
    float* out = (float*)d_out;

    const int n = in_sizes[0] / 64;   // 65536 rows
    rbfn_fused<<<n / 128, 512, 0, stream>>>(x, centers, W, b, out);
}

// Round 11
// 75.597 us; speedup vs baseline: 100.1437x; 100.1437x over previous
//
#include <hip/hip_runtime.h>
#include <math.h>

typedef short bf16x8 __attribute__((ext_vector_type(8)));
typedef float f32x4 __attribute__((ext_vector_type(4)));
typedef unsigned int uint32;

#define BETA 10.0f
#define THRESH -88.0f
// PER-ELEMENT 32-dim certificate (R10's decomposed-max bound was the bug:
// it fired ~always at 32 dims). Here, per accumulator element:
//   proxy = 20*acc - 10*||x_r||^2_32 - 10*||c_j||^2_32 = -10*d2_32 + eps,
//   |eps| <= ~10 (bf16 rtne dot + Gram-diag norms).
// true arg64 = -10*d2_64 <= -10*d2_32 <= proxy + 10. Skip when proxy <= -88
// => arg64 <= -78 => contribution <= exp(-78)*1024*0.02 ~ 2e-32 << 1.5e-2.
// P(fire) = P(d2_32 < ~8.8) ~ 1.6e-9/pair -> ~0.1 expected over all 67M
// pairs; a firing costs one per-ct cold block (16 cols, exact fp32, ~2us).

// LDS map (74.25 KB -> 2 blocks/CU with VGPR <= 128)
#define C_OFF   0        // 65536 B: centers lo-32-dim bf16, chunk layout
#define XB_OFF  65536    // 8192 B: x lo-32-dim bf16, chunk layout (128 rows)
#define W_OFF   73728    // 768 B: W_x fp32 [3][64]
#define RED_OFF 74496    // 1536 B: out accumulator [128][3]
#define LDS_TOT 76032

__device__ __forceinline__ uint32 f2bf_rtne(float f) {
    uint32 u = __float_as_uint(f);
    u += 0x7FFFu + ((u >> 16) & 1u);
    return u >> 16;
}
__device__ __forceinline__ uint32 pk_rtne(float a, float b) {
    return f2bf_rtne(a) | (f2bf_rtne(b) << 16);
}
#define MFMA __builtin_amdgcn_mfma_f32_16x16x32_bf16

// Single kernel. Block = 128 rows x 1024 centers, certificate over dims
// 0..31, exact fallback over all 64. 512 thr = 8 waves; wave = all 128 rows
// x 128-col group. Grid 512 = 2 blocks/CU (independent phase interleaving).
__global__ __launch_bounds__(512, 4) void rbfn_fused(
    const float* __restrict__ x,
    const float* __restrict__ centers,
    const float* __restrict__ W,
    const float* __restrict__ bias,
    float* __restrict__ out)
{
    __shared__ __align__(16) char lds[LDS_TOT];

    const int tid = threadIdx.x;
    const int wv = tid >> 6;
    const int lane = tid & 63;
    const int quad = lane >> 4;
    const int l15 = lane & 15;
    const int row0 = blockIdx.x * 128;
    const f32x4 z = {0.f, 0.f, 0.f, 0.f};

    const float bb0 = bias[0], bb1 = bias[1], bb2 = bias[2];

    // ---- stage centers lo-half -> bf16 chunk layout (full-line reads) ----
    #pragma unroll
    for (int i = 0; i < 16; ++i) {
        const int f = i * 512 + tid;
        const int j = f >> 3, sg = f & 7;
        const float4 v = *((const float4*)centers + j * 16 + sg);
        uint2 q; q.x = pk_rtne(v.x, v.y); q.y = pk_rtne(v.z, v.w);
        *(uint2*)(lds + C_OFF + (j >> 4) * 1024 + (sg >> 1) * 256 +
                  (j & 15) * 16 + (sg & 1) * 8) = q;
    }
    // ---- stage x lo-half (128 rows) -> bf16 chunk layout ----
    #pragma unroll
    for (int i = 0; i < 2; ++i) {
        const int f = i * 512 + tid;
        const int r = f >> 3, sg = f & 7;
        const float4 v = *((const float4*)(x + (size_t)row0 * 64) + r * 16 + sg);
        uint2 q; q.x = pk_rtne(v.x, v.y); q.y = pk_rtne(v.z, v.w);
        *(uint2*)(lds + XB_OFF + (r >> 4) * 1024 + (sg >> 1) * 256 +
                  (r & 15) * 16 + (sg & 1) * 8) = q;
    }
    // ---- W_x (3x64 fp32) -> LDS ----
    if (tid < 48) {
        const int k = tid >> 4, c = tid & 15;
        *((float4*)(lds + W_OFF) + tid) = *((const float4*)(W + k * 1088) + c);
    }
    __syncthreads();   // barrier 1: staging complete

    // ---- exact fp32 x@Wx^T + bias -> red. thread = (row r, quarter e) ----
    {
        const int r = tid >> 2, e = tid & 3;
        const float4* xr = (const float4*)(x + (size_t)(row0 + r) * 64) + e * 4;
        const float4 a0 = xr[0], a1 = xr[1], a2 = xr[2], a3 = xr[3];
        const float4 av[4] = {a0, a1, a2, a3};
        float d0 = 0.f, d1 = 0.f, d2 = 0.f;
        #pragma unroll
        for (int i = 0; i < 4; ++i) {
            const float4 a = av[i];
            const float4 w0 = *((const float4*)(lds + W_OFF) + 0 * 16 + e * 4 + i);
            const float4 w1 = *((const float4*)(lds + W_OFF) + 1 * 16 + e * 4 + i);
            const float4 w2 = *((const float4*)(lds + W_OFF) + 2 * 16 + e * 4 + i);
            d0 = fmaf(a.w, w0.w, fmaf(a.z, w0.z, fmaf(a.y, w0.y, fmaf(a.x, w0.x, d0))));
            d1 = fmaf(a.w, w1.w, fmaf(a.z, w1.z, fmaf(a.y, w1.y, fmaf(a.x, w1.x, d1))));
            d2 = fmaf(a.w, w2.w, fmaf(a.z, w2.z, fmaf(a.y, w2.y, fmaf(a.x, w2.x, d2))));
        }
        #pragma unroll
        for (int m = 1; m <= 2; m <<= 1) {
            d0 += __shfl_xor(d0, m);
            d1 += __shfl_xor(d1, m);
            d2 += __shfl_xor(d2, m);
        }
        if (e == 0) {
            float* red = (float*)(lds + RED_OFF);
            red[r * 3 + 0] = d0 + bb0;
            red[r * 3 + 1] = d1 + bb1;
            red[r * 3 + 2] = d2 + bb2;
        }
    }

    // ---- A fragments (lo 32 dims): contiguous b128 stripes ----
    bf16x8 af[8];
    #pragma unroll
    for (int rt = 0; rt < 8; ++rt)
        af[rt] = *(const bf16x8*)(lds + XB_OFF + rt * 1024 + quad * 256 + l15 * 16);

    // ---- per-element row norms: pr[rt][reg] = -10*||x_{rt*16+quad*4+reg}||^2
    f32x4 pr[8];
    #pragma unroll
    for (int rt = 0; rt < 8; ++rt) {
        const f32x4 d = MFMA(af[rt], af[rt], z, 0, 0, 0);
        f32x4 p;
        #pragma unroll
        for (int reg = 0; reg < 4; ++reg)
            p[reg] = -BETA * __shfl(d[reg], quad * 20 + reg);
        pr[rt] = p;
    }

    // ---- B fragments + -10*||c_j||^2_32 via Gram diagonal ----
    bf16x8 bf[8];
    float c2r[8];
    #pragma unroll
    for (int ct = 0; ct < 8; ++ct) {
        bf[ct] = *(const bf16x8*)(lds + C_OFF + (wv * 8 + ct) * 1024 +
                                  quad * 256 + l15 * 16);
        const f32x4 d = MFMA(bf[ct], bf[ct], z, 0, 0, 0);
        const float dv = (l15 & 2) ? ((l15 & 1) ? d[3] : d[2])
                                   : ((l15 & 1) ? d[1] : d[0]);
        c2r[ct] = -BETA * __shfl(dv, (l15 >> 2) * 16 + l15);
    }
    __syncthreads();   // barrier 2: red seeded before any cold atomics

    // ---- hot loop: per-ct tight certificate; cold handles ONLY that ct ----
    #pragma unroll
    for (int ct = 0; ct < 8; ++ct) {
        const bf16x8 b = bf[ct];
        f32x4 mx = {-1e30f, -1e30f, -1e30f, -1e30f};
        #pragma unroll
        for (int rt = 0; rt < 8; ++rt) {
            const f32x4 acc = MFMA(af[rt], b, z, 0, 0, 0);
            #pragma unroll
            for (int reg = 0; reg < 4; ++reg)
                mx[reg] = fmaxf(mx[reg], fmaf(20.0f, acc[reg], pr[rt][reg]));
        }
        const float bct = fmaxf(fmaxf(mx[0], mx[1]), fmaxf(mx[2], mx[3])) + c2r[ct];

        if (__builtin_expect(__ballot(bct > THRESH) != 0ull, 0)) {
            // cold: exact fp32, this ct's 16 cols x all 128 rows
            float* red = (float*)(lds + RED_OFF);
            const int j = wv * 128 + ct * 16 + l15;
            const float w0 = W[0 * 1088 + 64 + j];
            const float w1 = W[1 * 1088 + 64 + j];
            const float w2 = W[2 * 1088 + 64 + j];
            const float* cr = centers + (size_t)j * 64;
            #pragma clang loop unroll(disable)
            for (int rr = 0; rr < 32; ++rr) {
                const int r = quad * 32 + rr;
                const float* xr = x + (size_t)(row0 + r) * 64;
                float d2 = 0.f;
                #pragma clang loop unroll(disable)
                for (int k = 0; k < 64; ++k) {
                    const float df = xr[k] - cr[k];
                    d2 = fmaf(df, df, d2);
                }
                const float arg = -BETA * d2;
                if (arg > -87.f) {
                    const float e = expf(arg);
                    atomicAdd(&red[r * 3 + 0], e * w0);
                    atomicAdd(&red[r * 3 + 1], e * w1);
                    atomicAdd(&red[r * 3 + 2], e * w2);
                }
            }
        }
    }
    __syncthreads();   // barrier 3: red final

    // ---- coalesced float4 store ----
    if (tid < 96)
        ((float4*)out)[blockIdx.x * 96 + tid] = *((const float4*)(lds + RED_OFF) + tid);
}

extern "C" void kernel_launch(void* const* d_in, const int* in_sizes, int n_in,
                              void* d_out, int out_size, void* d_ws, size_t ws_size,
                              hipStream_t stream) {
    const float* x       = (const float*)d_in[0];
    const float* centers = (const float*)d_in[1];
    const float* W       = (const float*)d_in[2];
    const float* b       = (const float*)d_in[3];
    float* out = (float*)d_out;

    const int n = in_sizes[0] / 64;   // 65536 rows
    rbfn_fused<<<n / 128, 512, 0, stream>>>(x, centers, W, b, out);
}